// Round 2
// baseline (1156.220 us; speedup 1.0000x reference)
//
#include <hip/hip_runtime.h>

#define NROWS 32768   // B*T
#define PD    512     // P_DIM
#define NCB   8       // NC
#define CSZ   256     // CS
#define TOTD  2048    // TOT
#define SIN   1792    // SELF_IN / SELF_OUT

typedef float  floatx4  __attribute__((ext_vector_type(4)));
typedef __bf16 bf16x8_t __attribute__((ext_vector_type(8)));

__device__ __forceinline__ unsigned short f2bf(float f) {
    unsigned int u = __float_as_uint(f);
    u += 0x7FFFu + ((u >> 16) & 1u);     // round-to-nearest-even
    return (unsigned short)(u >> 16);
}
__device__ __forceinline__ float bf2f(unsigned int h) {
    return __uint_as_float(h << 16);
}

// ---------------- f32 -> bf16 conversion (vectorized) ----------------
__global__ __launch_bounds__(256) void k_cvt(const float* __restrict__ in,
                                             unsigned short* __restrict__ out,
                                             int n4) {
    int i = blockIdx.x * 256 + threadIdx.x;
    if (i >= n4) return;
    float4 v = ((const float4*)in)[i];
    ushort4 o;
    o.x = f2bf(v.x); o.y = f2bf(v.y); o.z = f2bf(v.z); o.w = f2bf(v.w);
    ((ushort4*)out)[i] = o;
}

// -------- transpose linear_self (1792x1792) f32 -> bf16, LSTb[in][out] --------
// causal mask NOT applied: epilogue loop bound c < col>>8 enforces it exactly.
__global__ __launch_bounds__(256) void k_tb(const float* __restrict__ in,
                                            unsigned short* __restrict__ out) {
    __shared__ float t[32][33];
    int bx = blockIdx.x * 32, by = blockIdx.y * 32;
    int tx = threadIdx.x & 31, ty = threadIdx.x >> 5;   // 32 x 8
#pragma unroll
    for (int j = 0; j < 32; j += 8)
        t[ty + j][tx] = in[(size_t)(by + ty + j) * SIN + bx + tx];
    __syncthreads();
#pragma unroll
    for (int j = 0; j < 32; j += 8)
        out[(size_t)(bx + ty + j) * SIN + by + tx] = f2bf(t[tx][ty + j]);
}

// ---------------- GEMM1: H = relu(pred @ W1^T + b1 + self_gather) -> bf16 ----------------
__global__ __launch_bounds__(256) void k_gemm1(const unsigned short* __restrict__ A,
                                               const unsigned short* __restrict__ Bw,
                                               const float* __restrict__ bias,
                                               const unsigned short* __restrict__ LSTb, // [1792][1792] bf16 transposed
                                               const int* __restrict__ idx,             // [NROWS][8]
                                               unsigned short* __restrict__ Out) {
    const int K = PD;
    // LDS in MFMA-fragment order: chunk = mtile*64 + q*16 + m ; 8 bf16 per chunk
    __shared__ __align__(16) unsigned short As[128 * 32];
    __shared__ __align__(16) unsigned short Bs[128 * 32];
    __shared__ int sidx[128 * NCB];

    const int tid  = threadIdx.x;
    const int lane = tid & 63;
    const int wave = tid >> 6;
    const int wm = (wave >> 1) << 6;       // wave row offset in 128-tile
    const int wn = (wave & 1) << 6;        // wave col offset
    const int row0 = blockIdx.y << 7;
    const int col0 = blockIdx.x << 7;

    floatx4 acc[4][4] = {};

    const int r0 = tid >> 2, q0 = tid & 3;
    const size_t a_g0 = (size_t)(row0 + r0) * K + q0 * 8;
    const size_t b_g0 = (size_t)(col0 + r0) * K + q0 * 8;
    const int lds0 = ((r0 >> 4) << 6) + (q0 << 4) + (r0 & 15);

    for (int i = tid; i < 128 * NCB; i += 256) sidx[i] = idx[(size_t)row0 * NCB + i];

    for (int k0 = 0; k0 < K; k0 += 32) {
        uint4 va0 = *(const uint4*)(A + a_g0 + k0);
        uint4 va1 = *(const uint4*)(A + a_g0 + (size_t)64 * K + k0);
        uint4 vb0 = *(const uint4*)(Bw + b_g0 + k0);
        uint4 vb1 = *(const uint4*)(Bw + b_g0 + (size_t)64 * K + k0);
        ((uint4*)As)[lds0]       = va0;
        ((uint4*)As)[lds0 + 256] = va1;
        ((uint4*)Bs)[lds0]       = vb0;
        ((uint4*)Bs)[lds0 + 256] = vb1;
        __syncthreads();

        bf16x8_t af[4], bfr[4];
        const bf16x8_t* Ap = (const bf16x8_t*)As;
        const bf16x8_t* Bp = (const bf16x8_t*)Bs;
#pragma unroll
        for (int mt = 0; mt < 4; ++mt) af[mt] = Ap[((wm >> 4) + mt) * 64 + lane];
#pragma unroll
        for (int nt = 0; nt < 4; ++nt) bfr[nt] = Bp[((wn >> 4) + nt) * 64 + lane];
#pragma unroll
        for (int mt = 0; mt < 4; ++mt)
#pragma unroll
            for (int nt = 0; nt < 4; ++nt)
                acc[mt][nt] = __builtin_amdgcn_mfma_f32_16x16x32_bf16(af[mt], bfr[nt], acc[mt][nt], 0, 0, 0);
        __syncthreads();
    }

    // epilogue: C[row = (lane>>4)*4 + reg][col = lane&15] per 16x16 tile
#pragma unroll
    for (int mt = 0; mt < 4; ++mt) {
        const int rowb = wm + mt * 16 + ((lane >> 4) << 2);
#pragma unroll
        for (int nt = 0; nt < 4; ++nt) {
            const int col = col0 + wn + nt * 16 + (lane & 15);
            const float bcol = bias[col];
            const int g = col >> 8;
#pragma unroll
            for (int r = 0; r < 4; ++r) {
                const int lrow = rowb + r;
                float v = acc[mt][nt][r] + bcol;
                for (int c = 0; c < g; ++c) {            // causal self-contribution
                    int ic = sidx[lrow * NCB + c];
                    if (ic >= 0)
                        v += bf2f(LSTb[(size_t)(c * CSZ + ic) * SIN + (col - CSZ)]);
                }
                v = fmaxf(v, 0.f);
                Out[(size_t)(row0 + lrow) * TOTD + col] = f2bf(v);
            }
        }
    }
}

// ---------------- per-row LayerNorm (in place, bf16) ----------------
__global__ __launch_bounds__(256) void k_ln(unsigned short* __restrict__ H,
                                            const float* __restrict__ gamma,
                                            const float* __restrict__ beta) {
    const int row = blockIdx.x;
    const int tid = threadIdx.x;
    unsigned short* rp = H + (size_t)row * TOTD;
    uint4 raw = ((const uint4*)rp)[tid];
    float x[8];
    x[0] = bf2f(raw.x & 0xFFFF); x[1] = bf2f(raw.x >> 16);
    x[2] = bf2f(raw.y & 0xFFFF); x[3] = bf2f(raw.y >> 16);
    x[4] = bf2f(raw.z & 0xFFFF); x[5] = bf2f(raw.z >> 16);
    x[6] = bf2f(raw.w & 0xFFFF); x[7] = bf2f(raw.w >> 16);
    float s = 0.f, ss = 0.f;
#pragma unroll
    for (int e = 0; e < 8; ++e) { s += x[e]; ss += x[e] * x[e]; }
#pragma unroll
    for (int o = 32; o; o >>= 1) { s += __shfl_xor(s, o); ss += __shfl_xor(ss, o); }
    __shared__ float ws4[4], wss4[4];
    if ((tid & 63) == 0) { ws4[tid >> 6] = s; wss4[tid >> 6] = ss; }
    __syncthreads();
    s  = ws4[0] + ws4[1] + ws4[2] + ws4[3];
    ss = wss4[0] + wss4[1] + wss4[2] + wss4[3];
    const float mu = s * (1.f / TOTD);
    const float var = ss * (1.f / TOTD) - mu * mu;
    const float rstd = rsqrtf(var + 1e-5f);
    unsigned int o32[4];
#pragma unroll
    for (int p = 0; p < 4; ++p) {
        int col = tid * 8 + p * 2;
        float y0 = (x[p * 2] - mu) * rstd * gamma[col] + beta[col];
        float y1 = (x[p * 2 + 1] - mu) * rstd * gamma[col + 1] + beta[col + 1];
        o32[p] = (unsigned int)f2bf(y0) | ((unsigned int)f2bf(y1) << 16);
    }
    uint4 o; o.x = o32[0]; o.y = o32[1]; o.z = o32[2]; o.w = o32[3];
    ((uint4*)rp)[tid] = o;
}

// ------- GEMM2 fused: logits tile (128 rows x one 256-col group) + log-softmax -------
// block = (group g, row-block); computes full softmax group in-epilogue; atomicAdd results.
__global__ __launch_bounds__(256, 2) void k_gemm2(const unsigned short* __restrict__ H,
                                                  const unsigned short* __restrict__ W2,
                                                  const float* __restrict__ b2,
                                                  const int* __restrict__ idx,
                                                  float* __restrict__ out) {
    const int K = TOTD;
    __shared__ __align__(16) unsigned short As[128 * 32];   // 8 KB
    __shared__ __align__(16) unsigned short Bs[256 * 32];   // 16 KB
    __shared__ float rmax[4 * 16];
    __shared__ float rsum[4 * 16];
    __shared__ int   tidx[128];
    __shared__ float wred[8];

    const int tid  = threadIdx.x;
    const int lane = tid & 63;
    const int wave = tid >> 6;
    const int g    = blockIdx.x;          // codebook group 0..7
    const int row0 = blockIdx.y << 7;
    const int col0 = g << 8;
    const int wn   = wave << 6;           // wave col offset within group

    floatx4 acc[8][4] = {};

    const int r0 = tid >> 2, q0 = tid & 3;
    const size_t a_g0 = (size_t)(row0 + r0) * K + q0 * 8;
    const size_t b_g0 = (size_t)(col0 + r0) * K + q0 * 8;
    const int lds0 = ((r0 >> 4) << 6) + (q0 << 4) + (r0 & 15);

    if (tid < 128) tidx[tid] = idx[(size_t)(row0 + tid) * NCB + g];

    for (int k0 = 0; k0 < K; k0 += 32) {
        uint4 va0 = *(const uint4*)(H  + a_g0 + k0);
        uint4 va1 = *(const uint4*)(H  + a_g0 + (size_t)64 * K + k0);
        uint4 vb0 = *(const uint4*)(W2 + b_g0 + k0);
        uint4 vb1 = *(const uint4*)(W2 + b_g0 + (size_t)64  * K + k0);
        uint4 vb2 = *(const uint4*)(W2 + b_g0 + (size_t)128 * K + k0);
        uint4 vb3 = *(const uint4*)(W2 + b_g0 + (size_t)192 * K + k0);
        ((uint4*)As)[lds0]       = va0;
        ((uint4*)As)[lds0 + 256] = va1;
        ((uint4*)Bs)[lds0]       = vb0;
        ((uint4*)Bs)[lds0 + 256] = vb1;
        ((uint4*)Bs)[lds0 + 512] = vb2;
        ((uint4*)Bs)[lds0 + 768] = vb3;
        __syncthreads();

        const bf16x8_t* Ap = (const bf16x8_t*)As;
        const bf16x8_t* Bp = (const bf16x8_t*)Bs;
        bf16x8_t af[8], bfr[4];
#pragma unroll
        for (int mt = 0; mt < 8; ++mt) af[mt] = Ap[mt * 64 + lane];
#pragma unroll
        for (int nt = 0; nt < 4; ++nt) bfr[nt] = Bp[((wn >> 4) + nt) * 64 + lane];
#pragma unroll
        for (int mt = 0; mt < 8; ++mt)
#pragma unroll
            for (int nt = 0; nt < 4; ++nt)
                acc[mt][nt] = __builtin_amdgcn_mfma_f32_16x16x32_bf16(af[mt], bfr[nt], acc[mt][nt], 0, 0, 0);
        __syncthreads();
    }

    // ---- epilogue: per-16-row tile, cross-wave log-softmax over the 256-col group ----
    const int rl = (lane >> 4) << 2;      // row base within 16-tile
    const int cl = lane & 15;             // col within 16-tile
    float bcol[4];
#pragma unroll
    for (int nt = 0; nt < 4; ++nt) bcol[nt] = b2[col0 + wn + nt * 16 + cl];

    float llp = 0.f;
#pragma unroll
    for (int mt = 0; mt < 8; ++mt) {
        float v[4][4];                     // [nt][reg]
#pragma unroll
        for (int nt = 0; nt < 4; ++nt)
#pragma unroll
            for (int r = 0; r < 4; ++r) v[nt][r] = acc[mt][nt][r] + bcol[nt];
        float pm[4];
#pragma unroll
        for (int r = 0; r < 4; ++r) {
            pm[r] = fmaxf(fmaxf(v[0][r], v[1][r]), fmaxf(v[2][r], v[3][r]));
#pragma unroll
            for (int o = 1; o < 16; o <<= 1) pm[r] = fmaxf(pm[r], __shfl_xor(pm[r], o));
        }
        if (cl == 0) {
#pragma unroll
            for (int r = 0; r < 4; ++r) rmax[wave * 16 + rl + r] = pm[r];
        }
        __syncthreads();
        float gm[4], gs[4];
#pragma unroll
        for (int r = 0; r < 4; ++r) {
            gm[r] = fmaxf(fmaxf(rmax[rl + r], rmax[16 + rl + r]),
                          fmaxf(rmax[32 + rl + r], rmax[48 + rl + r]));
            float s = 0.f;
#pragma unroll
            for (int nt = 0; nt < 4; ++nt) s += __expf(v[nt][r] - gm[r]);
#pragma unroll
            for (int o = 1; o < 16; o <<= 1) s += __shfl_xor(s, o);
            gs[r] = s;
        }
        if (cl == 0) {
#pragma unroll
            for (int r = 0; r < 4; ++r) rsum[wave * 16 + rl + r] = gs[r];
        }
        __syncthreads();
#pragma unroll
        for (int r = 0; r < 4; ++r) {
            float tot = rsum[rl + r] + rsum[16 + rl + r] + rsum[32 + rl + r] + rsum[48 + rl + r];
            float logZ = gm[r] + __logf(tot);
            int ic = tidx[mt * 16 + rl + r];
#pragma unroll
            for (int nt = 0; nt < 4; ++nt)
                if (ic == wn + nt * 16 + cl) llp += v[nt][r] - logZ;
        }
        __syncthreads();   // protect rmax/rsum reuse next mt
    }

    float lcnt = (tid < 128 && tidx[tid] >= 0) ? 1.f : 0.f;
#pragma unroll
    for (int o = 1; o < 64; o <<= 1) { llp += __shfl_xor(llp, o); lcnt += __shfl_xor(lcnt, o); }
    if (lane == 0) { wred[wave] = llp; wred[4 + wave] = lcnt; }
    __syncthreads();
    if (tid == 0) {
        atomicAdd(&out[0], wred[0] + wred[1] + wred[2] + wred[3]);
        atomicAdd(&out[1], wred[4] + wred[5] + wred[6] + wred[7]);
    }
}

extern "C" void kernel_launch(void* const* d_in, const int* in_sizes, int n_in,
                              void* d_out, int out_size, void* d_ws, size_t ws_size,
                              hipStream_t stream) {
    const float* predictor = (const float*)d_in[0];
    const int*   cbidx     = (const int*)d_in[1];
    const float* W1        = (const float*)d_in[2];
    const float* b1        = (const float*)d_in[3];
    const float* LS        = (const float*)d_in[4];
    const float* gamma     = (const float*)d_in[5];
    const float* beta      = (const float*)d_in[6];
    const float* W2        = (const float*)d_in[7];
    const float* b2        = (const float*)d_in[8];
    float* out = (float*)d_out;

    char* ws = (char*)d_ws;
    size_t off = 0;
    auto alloc = [&](size_t bytes) {
        char* p = ws + off;
        off += (bytes + 255) & ~(size_t)255;
        return p;
    };
    unsigned short* pred16 = (unsigned short*)alloc((size_t)NROWS * PD * 2);   // 33.6 MB
    unsigned short* W1_16  = (unsigned short*)alloc((size_t)TOTD * PD * 2);    //  2.1 MB
    unsigned short* W2_16  = (unsigned short*)alloc((size_t)TOTD * TOTD * 2);  //  8.4 MB
    unsigned short* LSTb   = (unsigned short*)alloc((size_t)SIN * SIN * 2);    //  6.4 MB
    unsigned short* Hbuf   = (unsigned short*)alloc((size_t)NROWS * TOTD * 2); // 134.2 MB
    // total ~185 MB

    hipMemsetAsync(d_out, 0, 2 * sizeof(float), stream);

    k_cvt<<<NROWS * PD / 4 / 256, 256, 0, stream>>>(predictor, pred16, NROWS * PD / 4);
    k_cvt<<<TOTD * PD / 4 / 256, 256, 0, stream>>>(W1, W1_16, TOTD * PD / 4);
    k_cvt<<<TOTD * TOTD / 4 / 256, 256, 0, stream>>>(W2, W2_16, TOTD * TOTD / 4);
    k_tb<<<dim3(SIN / 32, SIN / 32), 256, 0, stream>>>(LS, LSTb);

    k_gemm1<<<dim3(TOTD / 128, NROWS / 128), 256, 0, stream>>>(pred16, W1_16, b1, LSTb, cbidx, Hbuf);
    k_ln<<<NROWS, 256, 0, stream>>>(Hbuf, gamma, beta);
    k_gemm2<<<dim3(NCB, NROWS / 128), 256, 0, stream>>>(Hbuf, W2_16, b2, cbidx, out);
}

// Round 3
// 804.072 us; speedup vs baseline: 1.4380x; 1.4380x over previous
//
#include <hip/hip_runtime.h>

#define NROWS 32768   // B*T
#define PD    512     // P_DIM
#define NCB   8       // NC
#define CSZ   256     // CS
#define TOTD  2048    // TOT
#define SIN   1792    // SELF_IN / SELF_OUT

typedef float  floatx4  __attribute__((ext_vector_type(4)));
typedef __bf16 bf16x8_t __attribute__((ext_vector_type(8)));

__device__ __forceinline__ unsigned short f2bf(float f) {
    unsigned int u = __float_as_uint(f);
    u += 0x7FFFu + ((u >> 16) & 1u);     // round-to-nearest-even
    return (unsigned short)(u >> 16);
}
__device__ __forceinline__ float bf2f(unsigned int h) {
    return __uint_as_float(h << 16);
}

// async global->LDS, 16B per lane; LDS dest = wave-uniform base + lane*16
__device__ __forceinline__ void gload16(const unsigned short* g, unsigned short* l) {
    __builtin_amdgcn_global_load_lds(
        (const __attribute__((address_space(1))) void*)g,
        (__attribute__((address_space(3))) void*)l, 16, 0, 0);
}

// ---------------- f32 -> bf16 conversion (vectorized) ----------------
__global__ __launch_bounds__(256) void k_cvt(const float* __restrict__ in,
                                             unsigned short* __restrict__ out,
                                             int n4) {
    int i = blockIdx.x * 256 + threadIdx.x;
    if (i >= n4) return;
    float4 v = ((const float4*)in)[i];
    ushort4 o;
    o.x = f2bf(v.x); o.y = f2bf(v.y); o.z = f2bf(v.z); o.w = f2bf(v.w);
    ((ushort4*)out)[i] = o;
}

// -------- transpose linear_self (1792x1792) f32 -> bf16, LSTb[in][out] --------
// causal mask NOT applied: k_ln's loop bound c < col>>8 enforces it exactly.
__global__ __launch_bounds__(256) void k_tb(const float* __restrict__ in,
                                            unsigned short* __restrict__ out) {
    __shared__ float t[32][33];
    int bx = blockIdx.x * 32, by = blockIdx.y * 32;
    int tx = threadIdx.x & 31, ty = threadIdx.x >> 5;   // 32 x 8
#pragma unroll
    for (int j = 0; j < 32; j += 8)
        t[ty + j][tx] = in[(size_t)(by + ty + j) * SIN + bx + tx];
    __syncthreads();
#pragma unroll
    for (int j = 0; j < 32; j += 8)
        out[(size_t)(bx + ty + j) * SIN + by + tx] = f2bf(t[tx][ty + j]);
}

// ---------------- GEMM1: Hraw = pred @ W1^T + b1 -> bf16 (no relu/self here) ----------------
__global__ __launch_bounds__(256) void k_gemm1(const unsigned short* __restrict__ A,
                                               const unsigned short* __restrict__ Bw,
                                               const float* __restrict__ bias,
                                               unsigned short* __restrict__ Out) {
    const int K = PD;
    // LDS fragment order: chunk = tile*64 + q*16 + m ; chunk holds X[row tile*16+m][k q*8..+7]
    __shared__ __align__(16) unsigned short As[128 * 32];
    __shared__ __align__(16) unsigned short Bs[128 * 32];

    const int tid  = threadIdx.x;
    const int lane = tid & 63;
    const int wave = tid >> 6;
    const int wm = (wave >> 1) << 6;
    const int wn = (wave & 1) << 6;
    const int row0 = blockIdx.y << 7;
    const int col0 = blockIdx.x << 7;

    floatx4 acc[4][4] = {};

    // global_load_lds: lane i of wave stages chunk (tile*64+i): row tile*16+(i&15), koff (i>>4)*8
    const int lm = lane & 15, lq = lane >> 4;
    const size_t aoff = (size_t)(row0 + wave * 16 + lm) * K + lq * 8;
    const size_t boff = (size_t)(col0 + wave * 16 + lm) * K + lq * 8;
    unsigned short* AsW0 = As + wave * 512;        // tile = wave
    unsigned short* AsW1 = As + (wave + 4) * 512;  // tile = wave+4
    unsigned short* BsW0 = Bs + wave * 512;
    unsigned short* BsW1 = Bs + (wave + 4) * 512;

    for (int k0 = 0; k0 < K; k0 += 32) {
        gload16(A  + aoff + k0, AsW0);
        gload16(A  + aoff + (size_t)64 * K + k0, AsW1);
        gload16(Bw + boff + k0, BsW0);
        gload16(Bw + boff + (size_t)64 * K + k0, BsW1);
        __syncthreads();

        bf16x8_t af[4], bfr[4];
        const bf16x8_t* Ap = (const bf16x8_t*)As;
        const bf16x8_t* Bp = (const bf16x8_t*)Bs;
#pragma unroll
        for (int mt = 0; mt < 4; ++mt) af[mt] = Ap[((wm >> 4) + mt) * 64 + lane];
#pragma unroll
        for (int nt = 0; nt < 4; ++nt) bfr[nt] = Bp[((wn >> 4) + nt) * 64 + lane];
#pragma unroll
        for (int mt = 0; mt < 4; ++mt)
#pragma unroll
            for (int nt = 0; nt < 4; ++nt)
                acc[mt][nt] = __builtin_amdgcn_mfma_f32_16x16x32_bf16(af[mt], bfr[nt], acc[mt][nt], 0, 0, 0);
        __syncthreads();
    }

    // epilogue: C[row=(lane>>4)*4+reg][col=lane&15] per 16x16 tile
#pragma unroll
    for (int mt = 0; mt < 4; ++mt) {
        const int rowb = row0 + wm + mt * 16 + ((lane >> 4) << 2);
#pragma unroll
        for (int nt = 0; nt < 4; ++nt) {
            const int col = col0 + wn + nt * 16 + (lane & 15);
            const float bcol = bias[col];
#pragma unroll
            for (int r = 0; r < 4; ++r)
                Out[(size_t)(rowb + r) * TOTD + col] = f2bf(acc[mt][nt][r] + bcol);
        }
    }
}

// -------- fused: self-gather + relu + LayerNorm (in place, bf16), 1 row/block --------
__global__ __launch_bounds__(256) void k_ln(unsigned short* __restrict__ H,
                                            const unsigned short* __restrict__ LSTb,
                                            const int* __restrict__ idx,
                                            const float* __restrict__ gamma,
                                            const float* __restrict__ beta) {
    const int row = blockIdx.x;
    const int tid = threadIdx.x;
    __shared__ int sidx[8];
    __shared__ float ws4[4], wss4[4];
    if (tid < 8) sidx[tid] = idx[(size_t)row * NCB + tid];

    unsigned short* rp = H + (size_t)row * TOTD;
    uint4 raw = ((const uint4*)rp)[tid];
    float x[8];
    x[0] = bf2f(raw.x & 0xFFFF); x[1] = bf2f(raw.x >> 16);
    x[2] = bf2f(raw.y & 0xFFFF); x[3] = bf2f(raw.y >> 16);
    x[4] = bf2f(raw.z & 0xFFFF); x[5] = bf2f(raw.z >> 16);
    x[6] = bf2f(raw.w & 0xFFFF); x[7] = bf2f(raw.w >> 16);
    __syncthreads();

    // self contribution: cols tid*8..+7, group gt = tid>>5; add LSTb rows c<gt
    const int gt = tid >> 5;
#pragma unroll
    for (int c = 0; c < 7; ++c) {
        if (c < gt) {
            int ic = sidx[c];
            if (ic >= 0) {
                uint4 v = *(const uint4*)(LSTb + (size_t)(c * CSZ + ic) * SIN + (tid * 8 - CSZ));
                x[0] += bf2f(v.x & 0xFFFF); x[1] += bf2f(v.x >> 16);
                x[2] += bf2f(v.y & 0xFFFF); x[3] += bf2f(v.y >> 16);
                x[4] += bf2f(v.z & 0xFFFF); x[5] += bf2f(v.z >> 16);
                x[6] += bf2f(v.w & 0xFFFF); x[7] += bf2f(v.w >> 16);
            }
        }
    }
#pragma unroll
    for (int e = 0; e < 8; ++e) x[e] = fmaxf(x[e], 0.f);

    float s = 0.f, ss = 0.f;
#pragma unroll
    for (int e = 0; e < 8; ++e) { s += x[e]; ss += x[e] * x[e]; }
#pragma unroll
    for (int o = 32; o; o >>= 1) { s += __shfl_xor(s, o); ss += __shfl_xor(ss, o); }
    if ((tid & 63) == 0) { ws4[tid >> 6] = s; wss4[tid >> 6] = ss; }
    __syncthreads();
    s  = ws4[0] + ws4[1] + ws4[2] + ws4[3];
    ss = wss4[0] + wss4[1] + wss4[2] + wss4[3];
    const float mu = s * (1.f / TOTD);
    const float var = ss * (1.f / TOTD) - mu * mu;
    const float rstd = rsqrtf(var + 1e-5f);
    unsigned int o32[4];
#pragma unroll
    for (int p = 0; p < 4; ++p) {
        int col = tid * 8 + p * 2;
        float y0 = (x[p * 2] - mu) * rstd * gamma[col] + beta[col];
        float y1 = (x[p * 2 + 1] - mu) * rstd * gamma[col + 1] + beta[col + 1];
        o32[p] = (unsigned int)f2bf(y0) | ((unsigned int)f2bf(y1) << 16);
    }
    uint4 o; o.x = o32[0]; o.y = o32[1]; o.z = o32[2]; o.w = o32[3];
    ((uint4*)rp)[tid] = o;
}

// ------- GEMM2 fused: logits tile (128 rows x one 256-col group) + log-softmax -------
__global__ __launch_bounds__(256, 2) void k_gemm2(const unsigned short* __restrict__ H,
                                                  const unsigned short* __restrict__ W2,
                                                  const float* __restrict__ b2,
                                                  const int* __restrict__ idx,
                                                  float* __restrict__ out) {
    const int K = TOTD;
    __shared__ __align__(16) unsigned short As[128 * 32];   // 8 KB
    __shared__ __align__(16) unsigned short Bs[256 * 32];   // 16 KB
    __shared__ float rmax[4 * 16];
    __shared__ float rsum[4 * 16];
    __shared__ int   tidx[128];
    __shared__ float wred[8];

    const int tid  = threadIdx.x;
    const int lane = tid & 63;
    const int wave = tid >> 6;
    const int g    = blockIdx.x;          // codebook group 0..7
    const int row0 = blockIdx.y << 7;
    const int col0 = g << 8;
    const int wn   = wave << 6;           // wave col offset within group

    floatx4 acc[8][4] = {};

    const int lm = lane & 15, lq = lane >> 4;
    const size_t aoff = (size_t)(row0 + wave * 16 + lm) * K + lq * 8;
    const size_t boff = (size_t)(col0 + wave * 16 + lm) * K + lq * 8;

    if (tid < 128) tidx[tid] = idx[(size_t)(row0 + tid) * NCB + g];

    for (int k0 = 0; k0 < K; k0 += 32) {
        gload16(H  + aoff + k0, As + wave * 512);
        gload16(H  + aoff + (size_t)64  * K + k0, As + (wave + 4)  * 512);
        gload16(W2 + boff + k0, Bs + wave * 512);
        gload16(W2 + boff + (size_t)64  * K + k0, Bs + (wave + 4)  * 512);
        gload16(W2 + boff + (size_t)128 * K + k0, Bs + (wave + 8)  * 512);
        gload16(W2 + boff + (size_t)192 * K + k0, Bs + (wave + 12) * 512);
        __syncthreads();

        const bf16x8_t* Ap = (const bf16x8_t*)As;
        const bf16x8_t* Bp = (const bf16x8_t*)Bs;
        bf16x8_t af[8], bfr[4];
#pragma unroll
        for (int mt = 0; mt < 8; ++mt) af[mt] = Ap[mt * 64 + lane];
#pragma unroll
        for (int nt = 0; nt < 4; ++nt) bfr[nt] = Bp[(wave * 4 + nt) * 64 + lane];
#pragma unroll
        for (int mt = 0; mt < 8; ++mt)
#pragma unroll
            for (int nt = 0; nt < 4; ++nt)
                acc[mt][nt] = __builtin_amdgcn_mfma_f32_16x16x32_bf16(af[mt], bfr[nt], acc[mt][nt], 0, 0, 0);
        __syncthreads();
    }

    // ---- epilogue: per-16-row tile, cross-wave log-softmax over the 256-col group ----
    const int rl = (lane >> 4) << 2;      // row base within 16-tile
    const int cl = lane & 15;             // col within 16-tile
    float bcol[4];
#pragma unroll
    for (int nt = 0; nt < 4; ++nt) bcol[nt] = b2[col0 + wn + nt * 16 + cl];

    float llp = 0.f;
#pragma unroll
    for (int mt = 0; mt < 8; ++mt) {
        float v[4][4];                     // [nt][reg]
#pragma unroll
        for (int nt = 0; nt < 4; ++nt)
#pragma unroll
            for (int r = 0; r < 4; ++r) v[nt][r] = acc[mt][nt][r] + bcol[nt];
        float pm[4];
#pragma unroll
        for (int r = 0; r < 4; ++r) {
            pm[r] = fmaxf(fmaxf(v[0][r], v[1][r]), fmaxf(v[2][r], v[3][r]));
#pragma unroll
            for (int o = 1; o < 16; o <<= 1) pm[r] = fmaxf(pm[r], __shfl_xor(pm[r], o));
        }
        if (cl == 0) {
#pragma unroll
            for (int r = 0; r < 4; ++r) rmax[wave * 16 + rl + r] = pm[r];
        }
        __syncthreads();
        float gm[4], gs[4];
#pragma unroll
        for (int r = 0; r < 4; ++r) {
            gm[r] = fmaxf(fmaxf(rmax[rl + r], rmax[16 + rl + r]),
                          fmaxf(rmax[32 + rl + r], rmax[48 + rl + r]));
            float s = 0.f;
#pragma unroll
            for (int nt = 0; nt < 4; ++nt) s += __expf(v[nt][r] - gm[r]);
#pragma unroll
            for (int o = 1; o < 16; o <<= 1) s += __shfl_xor(s, o);
            gs[r] = s;
        }
        if (cl == 0) {
#pragma unroll
            for (int r = 0; r < 4; ++r) rsum[wave * 16 + rl + r] = gs[r];
        }
        __syncthreads();
#pragma unroll
        for (int r = 0; r < 4; ++r) {
            float tot = rsum[rl + r] + rsum[16 + rl + r] + rsum[32 + rl + r] + rsum[48 + rl + r];
            float logZ = gm[r] + __logf(tot);
            int ic = tidx[mt * 16 + rl + r];
#pragma unroll
            for (int nt = 0; nt < 4; ++nt)
                if (ic == wn + nt * 16 + cl) llp += v[nt][r] - logZ;
        }
        __syncthreads();   // protect rmax/rsum reuse next mt
    }

    float lcnt = (tid < 128 && tidx[tid] >= 0) ? 1.f : 0.f;
#pragma unroll
    for (int o = 1; o < 64; o <<= 1) { llp += __shfl_xor(llp, o); lcnt += __shfl_xor(lcnt, o); }
    if (lane == 0) { wred[wave] = llp; wred[4 + wave] = lcnt; }
    __syncthreads();
    if (tid == 0) {
        atomicAdd(&out[0], wred[0] + wred[1] + wred[2] + wred[3]);
        atomicAdd(&out[1], wred[4] + wred[5] + wred[6] + wred[7]);
    }
}

extern "C" void kernel_launch(void* const* d_in, const int* in_sizes, int n_in,
                              void* d_out, int out_size, void* d_ws, size_t ws_size,
                              hipStream_t stream) {
    const float* predictor = (const float*)d_in[0];
    const int*   cbidx     = (const int*)d_in[1];
    const float* W1        = (const float*)d_in[2];
    const float* b1        = (const float*)d_in[3];
    const float* LS        = (const float*)d_in[4];
    const float* gamma     = (const float*)d_in[5];
    const float* beta      = (const float*)d_in[6];
    const float* W2        = (const float*)d_in[7];
    const float* b2        = (const float*)d_in[8];
    float* out = (float*)d_out;

    char* ws = (char*)d_ws;
    size_t off = 0;
    auto alloc = [&](size_t bytes) {
        char* p = ws + off;
        off += (bytes + 255) & ~(size_t)255;
        return p;
    };
    unsigned short* pred16 = (unsigned short*)alloc((size_t)NROWS * PD * 2);   // 33.6 MB
    unsigned short* W1_16  = (unsigned short*)alloc((size_t)TOTD * PD * 2);    //  2.1 MB
    unsigned short* W2_16  = (unsigned short*)alloc((size_t)TOTD * TOTD * 2);  //  8.4 MB
    unsigned short* LSTb   = (unsigned short*)alloc((size_t)SIN * SIN * 2);    //  6.4 MB
    unsigned short* Hbuf   = (unsigned short*)alloc((size_t)NROWS * TOTD * 2); // 134.2 MB

    hipMemsetAsync(d_out, 0, 2 * sizeof(float), stream);

    k_cvt<<<NROWS * PD / 4 / 256, 256, 0, stream>>>(predictor, pred16, NROWS * PD / 4);
    k_cvt<<<TOTD * PD / 4 / 256, 256, 0, stream>>>(W1, W1_16, TOTD * PD / 4);
    k_cvt<<<TOTD * TOTD / 4 / 256, 256, 0, stream>>>(W2, W2_16, TOTD * TOTD / 4);
    k_tb<<<dim3(SIN / 32, SIN / 32), 256, 0, stream>>>(LS, LSTb);

    k_gemm1<<<dim3(TOTD / 128, NROWS / 128), 256, 0, stream>>>(pred16, W1_16, b1, Hbuf);
    k_ln<<<NROWS, 256, 0, stream>>>(Hbuf, LSTb, cbidx, gamma, beta);
    k_gemm2<<<dim3(NCB, NROWS / 128), 256, 0, stream>>>(Hbuf, W2_16, b2, cbidx, out);
}